// Round 1
// baseline (24.469 us; speedup 1.0000x reference)
//
#include <hip/hip_runtime.h>
#include <math.h>

namespace {

constexpr int Lc = 10;
constexpr int Vc = 32;
constexpr int Bc = 128;
constexpr int NC = 1024;          // 2^L deletion combos
constexpr float FMIN = -3.402823466e38f;   // np.finfo(float32).min

__global__ __launch_bounds__(256)
void del_channel(const float* __restrict__ messages,  // B*L*V
                 const float* __restrict__ logits,    // B*L*V (log-softmaxed)
                 const int*   __restrict__ mask,      // B*L (0/1)
                 float* __restrict__ out)             // 4*B*L*V
{
  const int b   = blockIdx.x;
  const int tid = threadIdx.x;
  const int nthr = 256;

  __shared__ float S[Lc * Lc];          // unnormalized group sums W_raw
  __shared__ float Wn[Lc][Lc];          // normalized combo weights (linear)
  __shared__ float pndl[Lc + 1][Lc + 1];// binomial length probs (linear)
  __shared__ float lg[Lc][Vc];          // this row's logits
  __shared__ float rsne[Lc];            // sum_v exp(logits[i][1..31])
  __shared__ float pn[Lc][Vc - 1];      // non-eos probs (normalized)
  __shared__ float elin[Lc][Vc - 1];    // expected (linear)
  __shared__ float erow[Lc];            // row sums of elin
  __shared__ float plen[Lc + 1];        // exp(length_logits)
  __shared__ float adjlen[Lc + 1];      // log adjusted length dist
  __shared__ float eadj[Lc];            // eos_adj columns
  __shared__ float l1madj[Lc];          // log1p(-exp(eos_adj))
  __shared__ int   ordv[Lc];
  __shared__ int   ndel_s;

  const float* msg_b = messages + (size_t)b * Lc * Vc;
  const float* log_b = logits   + (size_t)b * Lc * Vc;
  float* out_noisy = out + (size_t)b * Lc * Vc;
  float* out_adj   = out + (size_t)(Bc + b) * Lc * Vc;
  float* out_msg   = out + (size_t)(2 * Bc + b) * Lc * Vc;
  float* out_log   = out + (size_t)(3 * Bc + b) * Lc * Vc;

  // ---- phase 0: zero S, load logits to LDS, passthrough copies ----
  if (tid < Lc * Lc) S[tid] = 0.f;
  for (int idx = tid; idx < Lc * Vc; idx += nthr) {
    float lv = log_b[idx];
    ((float*)lg)[idx] = lv;
    out_log[idx] = lv;
    out_msg[idx] = msg_b[idx];
  }
  __syncthreads();

  // ---- phase 1: enumerate 1024 combos -> S ; pndl ; rsne ; order ----
  const float logP   = -2.302585092994046f;    // log(0.1)
  const float log1mP = -0.10536051565782628f;  // log(0.9)

  for (int c = tid; c < NC; c += nthr) {
    int n = __popc(c);
    float w = __expf((float)n * logP + (float)(Lc - n) * log1mP);
    int ord[Lc];
#pragma unroll
    for (int j = 0; j < Lc; ++j) ord[j] = j;
    // perm construction: for i=1..L-1, idx=L-1-i, if combo bit set,
    // rotate ord[idx..L-1] left by one. combos[c, idx] == (c >> i) & 1.
#pragma unroll
    for (int i = 1; i < Lc; ++i) {
      const int idx = Lc - 1 - i;
      if ((c >> i) & 1) {
        int t = ord[idx];
#pragma unroll
        for (int k2 = idx; k2 < Lc - 1; ++k2) ord[k2] = ord[k2 + 1];
        ord[Lc - 1] = t;
      }
    }
#pragma unroll
    for (int i = 0; i < Lc; ++i) {
      if (Lc - 1 - i >= n) atomicAdd(&S[i * Lc + ord[i]], w);
    }
  }

  // binomial probs: pndl[n][m] = C(n, n-m) P^(n-m) (1-P)^m  (m<=n else 0)
  if (tid < (Lc + 1) * (Lc + 1)) {
    int n = tid / (Lc + 1), m = tid % (Lc + 1);
    float v = 0.f;
    if (m <= n) {
      int d = n - m;          // deletions
      float C = 1.f;
      for (int t = 1; t <= d; ++t) C = C * (float)(n - d + t) / (float)t;
      v = C * powf(0.1f, (float)d) * powf(0.9f, (float)m);
    }
    pndl[tid / (Lc + 1)][tid % (Lc + 1)] = v;
  }

  // non-eos row sums
  if (tid < Lc) {
    float s = 0.f;
    for (int v = 1; v < Vc; ++v) s += __expf(lg[tid][v]);
    rsne[tid] = s;
  }

  // message-shift permutation + n_del (one thread; trivial)
  if (tid == 0) {
    int om[Lc];
#pragma unroll
    for (int j = 0; j < Lc; ++j) om[j] = j;
    int nd = 0;
#pragma unroll
    for (int j = 0; j < Lc; ++j) nd += (mask[b * Lc + j] != 0) ? 1 : 0;
#pragma unroll
    for (int i = 1; i < Lc; ++i) {
      const int idx = Lc - 1 - i;
      if (mask[b * Lc + idx] != 0) {
        int t = om[idx];
#pragma unroll
        for (int k2 = idx; k2 < Lc - 1; ++k2) om[k2] = om[k2 + 1];
        om[Lc - 1] = t;
      }
    }
#pragma unroll
    for (int j = 0; j < Lc; ++j) ordv[j] = om[j];
    ndel_s = nd;
  }
  __syncthreads();

  // ---- phase 2: normalize W ; compute pn ; length logits -> plen ----
  if (tid < Lc * Lc) {
    int i = tid / Lc;
    float rs = 0.f;
    for (int k = 0; k < Lc; ++k) rs += S[i * Lc + k];
    Wn[i][tid % Lc] = S[tid] / rs;
  }
  for (int idx = tid; idx < Lc * (Vc - 1); idx += nthr) {
    int i = idx / (Vc - 1), v = idx % (Vc - 1);
    pn[i][v] = __expf(lg[i][v + 1]) / rsne[i];
  }
  if (tid == 0) {
    // length_logits (L+1 entries), then plen = exp(length_logits)
    float cum = 0.f;
    plen[0] = __expf(lg[0][0]);
    for (int i = 1; i < Lc; ++i) {
      cum += log1pf(-__expf(lg[i - 1][0]));
      float ll = lg[i][0] + fminf(fmaxf(cum, FMIN), 0.f);
      plen[i] = __expf(ll);
    }
    cum += log1pf(-__expf(lg[Lc - 1][0]));
    plen[Lc] = __expf(fminf(fmaxf(cum, FMIN), 0.f));
  }
  __syncthreads();

  // ---- phase 3: expected (linear) = Wn @ pn ----
  for (int idx = tid; idx < Lc * (Vc - 1); idx += nthr) {
    int i = idx / (Vc - 1), v = idx % (Vc - 1);
    float s = 0.f;
#pragma unroll
    for (int j = 0; j < Lc; ++j) s += Wn[i][j] * pn[j][v];
    elin[i][v] = s;
  }
  // adjusted length dist: adjlen[k] = log sum_n plen[n]*pndl[n][k]
  if (tid >= 64 && tid < 64 + Lc + 1) {
    int k = tid - 64;
    float s = 0.f;
#pragma unroll
    for (int n = 0; n <= Lc; ++n) s += plen[n] * pndl[n][k];
    adjlen[k] = logf(s);
  }
  __syncthreads();

  // ---- phase 4: erow ; eos_adj serial chain ----
  if (tid < Lc) {
    float s = 0.f;
    for (int v = 0; v < Vc - 1; ++v) s += elin[tid][v];
    erow[tid] = s;
  }
  if (tid == 64) {
    float c0 = adjlen[0];
    eadj[0] = c0;
    l1madj[0] = log1pf(-__expf(c0));
    float acc = l1madj[0];
    for (int i = 1; i < Lc; ++i) {
      float ai = fminf(fmaxf(adjlen[i] - acc, FMIN), 0.f);
      eadj[i] = ai;
      float l1 = log1pf(-__expf(ai));
      l1madj[i] = l1;
      acc = acc + l1;
    }
  }
  __syncthreads();

  // ---- phase 5: write noisy + adjusted ----
  for (int idx = tid; idx < Lc * Vc; idx += nthr) {
    int i = idx >> 5, v = idx & 31;
    float nv;
    if (i >= Lc - ndel_s) nv = (v == 0) ? 1.f : 0.f;
    else                  nv = msg_b[ordv[i] * Vc + v];
    out_noisy[idx] = nv;
    float av;
    if (v == 0) av = eadj[i];
    else        av = logf(elin[i][v - 1] / erow[i]) + l1madj[i];
    out_adj[idx] = av;
  }
}

} // namespace

extern "C" void kernel_launch(void* const* d_in, const int* in_sizes, int n_in,
                              void* d_out, int out_size, void* d_ws, size_t ws_size,
                              hipStream_t stream) {
  const float* messages = (const float*)d_in[0];
  const float* logits   = (const float*)d_in[1];
  const int*   mask     = (const int*)d_in[2];
  float* out = (float*)d_out;
  del_channel<<<Bc, 256, 0, stream>>>(messages, logits, mask, out);
}

// Round 2
// 14.617 us; speedup vs baseline: 1.6740x; 1.6740x over previous
//
#include <hip/hip_runtime.h>
#include <math.h>

namespace {

constexpr int Lc = 10;
constexpr int Vc = 32;
constexpr int Bc = 128;
constexpr float FMIN = -3.402823466e38f;   // np.finfo(float32).min

__global__ __launch_bounds__(256)
void del_channel(const float* __restrict__ messages,  // B*L*V
                 const float* __restrict__ logits,    // B*L*V (log-softmaxed)
                 const int*   __restrict__ mask,      // B*L (0/1)
                 float* __restrict__ out)             // 4*B*L*V
{
  const int b   = blockIdx.x;
  const int tid = threadIdx.x;

  __shared__ float e[Lc][Vc - 1];   // exp(non-eos logits), unnormalized
  __shared__ float Wf[Lc][Lc];      // row-normalized W / rsne[j]  (folded)
  __shared__ float rsne[Lc];        // sum_v exp(logits[i][1..31])
  __shared__ float eadj[Lc];        // eos_adj columns (log)
  __shared__ float l1madj[Lc];      // log1p(-exp(eos_adj))
  __shared__ float adjlen[Lc + 1];  // log adjusted length dist
  __shared__ float plen[Lc + 1];    // exp(length_logits)
  __shared__ int   ordv[Lc];
  __shared__ int   ndel_s;

  const float* msg_b = messages + (size_t)b * Lc * Vc;
  const float* log_b = logits   + (size_t)b * Lc * Vc;
  float* out_noisy = out + (size_t)b * Lc * Vc;
  float* out_adj   = out + (size_t)(Bc + b) * Lc * Vc;
  float* out_msg   = out + (size_t)(2 * Bc + b) * Lc * Vc;
  float* out_log   = out + (size_t)(3 * Bc + b) * Lc * Vc;

  const int wave = tid >> 6;
  const int lane = tid & 63;

  if (wave >= 2) {
    // ---- waves 2..3: passthrough copies + e[][] staging ----
    for (int idx = tid - 128; idx < Lc * Vc; idx += 128) {
      float lv = log_b[idx];
      out_log[idx] = lv;
      out_msg[idx] = msg_b[idx];
      int i = idx >> 5, v = idx & 31;
      if (v > 0) e[i][v - 1] = __expf(lv);
    }
  } else if (wave == 0) {
    // ---- wave 0: rsne -> folded W rows ; shift permutation ----
    if (lane < Lc) {
      const int i = lane;
      float s = 0.f;
      for (int v = 1; v < Vc; ++v) s += __expf(log_b[i * Vc + v]);
      rsne[i] = s;                       // intra-wave visible below
    }
    if (lane == 16) {
      int om[Lc];
#pragma unroll
      for (int j = 0; j < Lc; ++j) om[j] = j;
      int nd = 0;
#pragma unroll
      for (int j = 0; j < Lc; ++j) nd += (mask[b * Lc + j] != 0);
#pragma unroll
      for (int i2 = 1; i2 < Lc; ++i2) {
        const int idx = Lc - 1 - i2;
        if (mask[b * Lc + idx] != 0) {
          int t = om[idx];
#pragma unroll
          for (int k2 = idx; k2 < Lc - 1; ++k2) om[k2] = om[k2 + 1];
          om[Lc - 1] = t;
        }
      }
#pragma unroll
      for (int j = 0; j < Lc; ++j) ordv[j] = om[j];
      ndel_s = nd;
    }
    if (lane < Lc) {
      // closed-form deletion weights:
      //   W_raw[i][j] = C(j, j-i) * P^(j-i) * (1-P)^(i+1)  for j >= i
      const int i = lane;
      float pw = 1.f;
#pragma unroll
      for (int t = 0; t <= Lc - 1; ++t) if (t <= i) pw *= 0.9f;  // (1-P)^(i+1)
      float C = 1.f, pd = 1.f, s = 0.f;
      float w[Lc];
#pragma unroll
      for (int j = 0; j < Lc; ++j) {
        float val = 0.f;
        if (j >= i) {
          if (j > i) { C = C * (float)j / (float)(j - i); pd *= 0.1f; }
          val = C * pd * pw;
        }
        w[j] = val; s += val;
      }
      float inv_s = 1.f / s;
#pragma unroll
      for (int j = 0; j < Lc; ++j)
        Wf[i][j] = w[j] * inv_s / rsne[j];   // rsne written above, same wave
    }
  } else {
    // ---- wave 1: length pipeline (plen -> pndl -> adjlen -> eos_adj) ----
    const int k = lane;
    float pnd[Lc + 1];                 // binomial column k, in registers
    if (k <= Lc) {
      float p9 = 1.f;
#pragma unroll
      for (int t = 0; t < Lc; ++t) if (t < k) p9 *= 0.9f;   // 0.9^k
      float C = 1.f, pd = 1.f;
#pragma unroll
      for (int n = 0; n <= Lc; ++n) {
        float val = 0.f;
        if (n >= k) {
          if (n > k) { C = C * (float)n / (float)(n - k); pd *= 0.1f; }
          val = C * pd * p9;           // C(n,n-k) P^(n-k) (1-P)^k
        }
        pnd[n] = val;
      }
    }
    if (lane == 0) {
      float cum = 0.f;
      plen[0] = __expf(log_b[0]);
#pragma unroll
      for (int i = 1; i < Lc; ++i) {
        cum += log1pf(-__expf(log_b[(i - 1) * Vc]));
        plen[i] = __expf(log_b[i * Vc] + fminf(cum, 0.f));
      }
      cum += log1pf(-__expf(log_b[(Lc - 1) * Vc]));
      plen[Lc] = __expf(fminf(cum, 0.f));
    }
    if (k <= Lc) {                     // plen visible: same wave, prog order
      float s = 0.f;
#pragma unroll
      for (int n = 0; n <= Lc; ++n) s += plen[n] * pnd[n];
      adjlen[k] = __logf(s);
    }
    if (lane == 0) {                   // adjlen visible: same wave
      float c0 = adjlen[0];
      eadj[0] = c0;
      float l1 = log1pf(-__expf(c0));
      l1madj[0] = l1;
      float acc = l1;
#pragma unroll
      for (int i = 1; i < Lc; ++i) {
        float ai = fminf(fmaxf(adjlen[i] - acc, FMIN), 0.f);
        eadj[i] = ai;
        float l2 = log1pf(-__expf(ai));
        l1madj[i] = l2;
        acc += l2;
      }
    }
  }
  __syncthreads();

  // ---- final: noisy + adjusted (expected is already ~softmax-normalized) ----
  for (int idx = tid; idx < Lc * Vc; idx += 256) {
    const int i = idx >> 5, v = idx & 31;
    float nv;
    if (i >= Lc - ndel_s) nv = (v == 0) ? 1.f : 0.f;
    else                  nv = msg_b[ordv[i] * Vc + v];
    out_noisy[idx] = nv;
    float av;
    if (v == 0) {
      av = eadj[i];
    } else {
      float s = 0.f;
#pragma unroll
      for (int j = 0; j < Lc; ++j) s += Wf[i][j] * e[j][v - 1];
      av = __logf(s) + l1madj[i];
    }
    out_adj[idx] = av;
  }
}

} // namespace

extern "C" void kernel_launch(void* const* d_in, const int* in_sizes, int n_in,
                              void* d_out, int out_size, void* d_ws, size_t ws_size,
                              hipStream_t stream) {
  const float* messages = (const float*)d_in[0];
  const float* logits   = (const float*)d_in[1];
  const int*   mask     = (const int*)d_in[2];
  float* out = (float*)d_out;
  del_channel<<<Bc, 256, 0, stream>>>(messages, logits, mask, out);
}

// Round 3
// 9.753 us; speedup vs baseline: 2.5089x; 1.4987x over previous
//
#include <hip/hip_runtime.h>
#include <math.h>

namespace {

constexpr int Lc = 10;
constexpr int Vc = 32;
constexpr int Bc = 128;
constexpr float FMIN = -3.402823466e38f;   // np.finfo(float32).min

__global__ __launch_bounds__(256)
void del_channel(const float* __restrict__ messages,  // B*L*V
                 const float* __restrict__ logits,    // B*L*V (log-softmaxed)
                 const int*   __restrict__ mask,      // B*L (0/1)
                 float* __restrict__ out)             // 4*B*L*V
{
  const int b   = blockIdx.x;
  const int tid = threadIdx.x;

  __shared__ float e[Lc][Vc - 1];   // exp(non-eos logits), unnormalized
  __shared__ float msg_s[Lc * Vc];  // staged messages row
  __shared__ float Wf[Lc][Lc];      // row-normalized W / rsne[j] (folded)
  __shared__ float rsne[Lc];        // sum_v exp(logits[i][1..31])
  __shared__ float Es[Lc];          // exp(eos logits)
  __shared__ float plen[Lc + 1];    // linear length dist
  __shared__ float As[Lc + 1];      // adjusted length dist (linear)
  __shared__ float ratio_s[Lc];     // exp(eos_adj) ratios
  __shared__ float eadj[Lc];        // eos_adj (log)
  __shared__ float l1madj[Lc];      // log1p(-exp(eos_adj))
  __shared__ int   ordv[Lc];
  __shared__ int   ndel_s;

  const float* msg_b = messages + (size_t)b * Lc * Vc;
  const float* log_b = logits   + (size_t)b * Lc * Vc;
  float* out_noisy = out + (size_t)b * Lc * Vc;
  float* out_adj   = out + (size_t)(Bc + b) * Lc * Vc;
  float* out_msg   = out + (size_t)(2 * Bc + b) * Lc * Vc;
  float* out_log   = out + (size_t)(3 * Bc + b) * Lc * Vc;

  const int wave = tid >> 6;
  const int lane = tid & 63;

  if (wave >= 2) {
    // ---- waves 2..3: vectorized passthrough copies + LDS staging ----
    const int t = tid - 128;                      // 0..127, need 80
    if (t < Lc * Vc / 4) {
      const float4 lv = ((const float4*)log_b)[t];
      ((float4*)out_log)[t] = lv;
      const float4 mv = ((const float4*)msg_b)[t];
      ((float4*)out_msg)[t] = mv;
      ((float4*)msg_s)[t]   = mv;
      const int base = t * 4;
      const float le[4] = {lv.x, lv.y, lv.z, lv.w};
#pragma unroll
      for (int j2 = 0; j2 < 4; ++j2) {
        const int idx = base + j2, i = idx >> 5, v = idx & 31;
        if (v > 0) e[i][v - 1] = __expf(le[j2]);
      }
    }
  } else if (wave == 0) {
    // ---- wave 0: rsne -> folded W rows ; shift permutation ----
    if (lane < Lc) {
      const int i = lane;
      float s0 = 0.f, s1 = 0.f, s2 = 0.f, s3 = 0.f;
      for (int v = 1; v < 29; v += 4) {
        s0 += __expf(log_b[i * Vc + v]);
        s1 += __expf(log_b[i * Vc + v + 1]);
        s2 += __expf(log_b[i * Vc + v + 2]);
        s3 += __expf(log_b[i * Vc + v + 3]);
      }
      s0 += __expf(log_b[i * Vc + 29]);
      s1 += __expf(log_b[i * Vc + 30]);
      s2 += __expf(log_b[i * Vc + 31]);
      rsne[i] = (s0 + s1) + (s2 + s3);
    }
    if (lane == 16) {
      int om[Lc];
#pragma unroll
      for (int j = 0; j < Lc; ++j) om[j] = j;
      int nd = 0;
#pragma unroll
      for (int j = 0; j < Lc; ++j) nd += (mask[b * Lc + j] != 0);
#pragma unroll
      for (int i2 = 1; i2 < Lc; ++i2) {
        const int idx = Lc - 1 - i2;
        if (mask[b * Lc + idx] != 0) {
          int t2 = om[idx];
#pragma unroll
          for (int k2 = idx; k2 < Lc - 1; ++k2) om[k2] = om[k2 + 1];
          om[Lc - 1] = t2;
        }
      }
#pragma unroll
      for (int j = 0; j < Lc; ++j) ordv[j] = om[j];
      ndel_s = nd;
    }
    if (lane < Lc) {
      // closed-form deletion weights:
      //   W_raw[i][j] = C(j, j-i) * P^(j-i) * (1-P)^(i+1)  for j >= i
      const int i = lane;
      float pw = 1.f;
#pragma unroll
      for (int t2 = 0; t2 < Lc; ++t2) if (t2 <= i) pw *= 0.9f;  // (1-P)^(i+1)
      float C = 1.f, pd = 1.f, s = 0.f;
      float w[Lc];
#pragma unroll
      for (int j = 0; j < Lc; ++j) {
        float val = 0.f;
        if (j >= i) {
          if (j > i) { C = C * (float)j / (float)(j - i); pd *= 0.1f; }
          val = C * pd * pw;
        }
        w[j] = val; s += val;
      }
      const float inv_s = 1.f / s;
#pragma unroll
      for (int j = 0; j < Lc; ++j)
        Wf[i][j] = w[j] * inv_s / rsne[j];   // rsne: same wave, prog order
    }
  } else {
    // ---- wave 1: length pipeline, all in LINEAR space ----
    const int k = lane;
    float pnd[Lc + 1];                 // binomial column k, in registers
    if (k <= Lc) {
      float p9 = 1.f;
#pragma unroll
      for (int t2 = 0; t2 < Lc; ++t2) if (t2 < k) p9 *= 0.9f;   // 0.9^k
      float C = 1.f, pd = 1.f;
#pragma unroll
      for (int n = 0; n <= Lc; ++n) {
        float val = 0.f;
        if (n >= k) {
          if (n > k) { C = C * (float)n / (float)(n - k); pd *= 0.1f; }
          val = C * pd * p9;           // C(n,n-k) P^(n-k) (1-P)^k
        }
        pnd[n] = val;
      }
    }
    if (k < Lc) Es[k] = __expf(log_b[k * Vc]);   // parallel eos exps
    if (lane == 0) {
      // plen[i] = E_i * prod_{k<i}(1-E_k); plen[L] = prod(1-E_k)
      float cp = 1.f;
      plen[0] = Es[0];
#pragma unroll
      for (int i = 1; i < Lc; ++i) {
        cp *= (1.f - Es[i - 1]);
        plen[i] = Es[i] * fminf(cp, 1.f);
      }
      cp *= (1.f - Es[Lc - 1]);
      plen[Lc] = fminf(cp, 1.f);
    }
    if (k <= Lc) {                     // plen visible: same wave, prog order
      float s = 0.f;
#pragma unroll
      for (int n = 0; n <= Lc; ++n) s += plen[n] * pnd[n];
      As[k] = s;                       // adjusted length dist, linear
    }
    if (lane == 0) {
      // serial remaining-mass chain: exp(acc_i) = rem_i
      float rem = 1.f;
#pragma unroll
      for (int i = 0; i < Lc; ++i) {
        const float ratio = fminf(As[i] / fmaxf(rem, 1e-30f), 1.f);
        ratio_s[i] = ratio;
        rem *= (1.f - ratio);
      }
    }
    if (k < Lc) {                      // parallel logs
      const float r = ratio_s[k];
      eadj[k]   = fmaxf(__logf(r), FMIN);
      l1madj[k] = log1pf(-r);
    }
  }
  __syncthreads();

  // ---- final: noisy + adjusted (expected already ~softmax-normalized) ----
  for (int idx = tid; idx < Lc * Vc; idx += 256) {
    const int i = idx >> 5, v = idx & 31;
    float nv;
    if (i >= Lc - ndel_s) nv = (v == 0) ? 1.f : 0.f;
    else                  nv = msg_s[ordv[i] * Vc + v];
    out_noisy[idx] = nv;
    float av;
    if (v == 0) {
      av = eadj[i];
    } else {
      float s = 0.f;
#pragma unroll
      for (int j = 0; j < Lc; ++j) s += Wf[i][j] * e[j][v - 1];
      av = __logf(s) + l1madj[i];
    }
    out_adj[idx] = av;
  }
}

} // namespace

extern "C" void kernel_launch(void* const* d_in, const int* in_sizes, int n_in,
                              void* d_out, int out_size, void* d_ws, size_t ws_size,
                              hipStream_t stream) {
  const float* messages = (const float*)d_in[0];
  const float* logits   = (const float*)d_in[1];
  const int*   mask     = (const int*)d_in[2];
  float* out = (float*)d_out;
  del_channel<<<Bc, 256, 0, stream>>>(messages, logits, mask, out);
}

// Round 4
// 9.749 us; speedup vs baseline: 2.5099x; 1.0004x over previous
//
#include <hip/hip_runtime.h>
#include <math.h>

namespace {

constexpr int Lc = 10;
constexpr int Vc = 32;
constexpr int Bc = 128;
constexpr float FMIN = -3.402823466e38f;   // np.finfo(float32).min

__global__ __launch_bounds__(256)
void del_channel(const float* __restrict__ messages,  // B*L*V
                 const float* __restrict__ logits,    // B*L*V (log-softmaxed)
                 const int*   __restrict__ mask,      // B*L (0/1)
                 float* __restrict__ out)             // 4*B*L*V
{
  const int b   = blockIdx.x;
  const int tid = threadIdx.x;

  __shared__ float e[Lc][Vc - 1];   // exp(non-eos logits), unnormalized
  __shared__ float msg_s[Lc * Vc];  // staged messages row
  __shared__ float Wf[Lc][Lc];      // row-normalized W * rinv[j] (folded)
  __shared__ float rinv[Lc];        // 1 / sum_v exp(logits[i][1..31])
  __shared__ float Es[Lc];          // exp(eos logits)
  __shared__ float plen[Lc + 1];    // linear length dist
  __shared__ float As[Lc + 1];      // adjusted length dist (linear)
  __shared__ float eadj[Lc];        // eos_adj (log)
  __shared__ float l1madj[Lc];      // log(1 - exp(eos_adj))
  __shared__ int   ordv[Lc];
  __shared__ int   ndel_s;

  const float* msg_b = messages + (size_t)b * Lc * Vc;
  const float* log_b = logits   + (size_t)b * Lc * Vc;
  float* out_noisy = out + (size_t)b * Lc * Vc;
  float* out_adj   = out + (size_t)(Bc + b) * Lc * Vc;
  float* out_msg   = out + (size_t)(2 * Bc + b) * Lc * Vc;
  float* out_log   = out + (size_t)(3 * Bc + b) * Lc * Vc;

  const int wave = tid >> 6;
  const int lane = tid & 63;

  if (wave >= 2) {
    // ---- waves 2..3: vectorized passthrough copies + LDS staging ----
    const int t = tid - 128;                      // 0..127, need 80
    if (t < Lc * Vc / 4) {
      const float4 lv = ((const float4*)log_b)[t];
      ((float4*)out_log)[t] = lv;
      const float4 mv = ((const float4*)msg_b)[t];
      ((float4*)out_msg)[t] = mv;
      ((float4*)msg_s)[t]   = mv;
      const int base = t * 4;
      const float le[4] = {lv.x, lv.y, lv.z, lv.w};
#pragma unroll
      for (int j2 = 0; j2 < 4; ++j2) {
        const int idx = base + j2, i = idx >> 5, v = idx & 31;
        if (v > 0) e[i][v - 1] = __expf(le[j2]);
      }
    }
  } else if (wave == 0) {
    // ---- wave 0: rinv (4 lanes/row, shfl-reduced) -> folded W ; perm ----
    if (lane < 4 * Lc) {
      const int i = lane >> 2, q = lane & 3;
      const float4 a  = ((const float4*)(log_b + i * Vc))[2 * q];
      const float4 b4 = ((const float4*)(log_b + i * Vc))[2 * q + 1];
      float s = ((q == 0) ? 0.f : __expf(a.x)) + __expf(a.y)
              + __expf(a.z) + __expf(a.w)
              + __expf(b4.x) + __expf(b4.y) + __expf(b4.z) + __expf(b4.w);
      s += __shfl_xor(s, 1);
      s += __shfl_xor(s, 2);
      if (q == 0) rinv[i] = __builtin_amdgcn_rcpf(s);
    }
    if (lane == 48) {
      int om[Lc];
#pragma unroll
      for (int j = 0; j < Lc; ++j) om[j] = j;
      int nd = 0;
#pragma unroll
      for (int j = 0; j < Lc; ++j) nd += (mask[b * Lc + j] != 0);
#pragma unroll
      for (int i2 = 1; i2 < Lc; ++i2) {
        const int idx = Lc - 1 - i2;
        if (mask[b * Lc + idx] != 0) {
          int t2 = om[idx];
#pragma unroll
          for (int k2 = idx; k2 < Lc - 1; ++k2) om[k2] = om[k2 + 1];
          om[Lc - 1] = t2;
        }
      }
#pragma unroll
      for (int j = 0; j < Lc; ++j) ordv[j] = om[j];
      ndel_s = nd;
    }
    if (lane < Lc) {
      // closed-form deletion weights:
      //   W_raw[i][j] = C(j, j-i) * P^(j-i) * (1-P)^(i+1)  for j >= i
      const int i = lane;
      float pw = 1.f;
#pragma unroll
      for (int t2 = 0; t2 < Lc; ++t2) if (t2 <= i) pw *= 0.9f;  // (1-P)^(i+1)
      float C = 1.f, pd = 1.f, s = 0.f;
      float w[Lc];
#pragma unroll
      for (int j = 0; j < Lc; ++j) {
        float val = 0.f;
        if (j >= i) {
          if (j > i) { C = __fdividef(C * (float)j, (float)(j - i)); pd *= 0.1f; }
          val = C * pd * pw;
        }
        w[j] = val; s += val;
      }
      const float inv_s = __builtin_amdgcn_rcpf(s);
#pragma unroll
      for (int j = 0; j < Lc; ++j)
        Wf[i][j] = w[j] * inv_s * rinv[j];   // rinv: same wave, prog order
    }
  } else {
    // ---- wave 1: length pipeline, fully lane-parallel in LINEAR space ----
    const int k = lane;
    if (k < Lc) Es[k] = __expf(log_b[k * Vc]);   // parallel eos exps
    float pnd[Lc + 1];                 // binomial column k, in registers
    if (k <= Lc) {
      float p9 = 1.f;
#pragma unroll
      for (int t2 = 0; t2 < Lc; ++t2) if (t2 < k) p9 *= 0.9f;   // 0.9^k
      float C = 1.f, pd = 1.f;
#pragma unroll
      for (int n = 0; n <= Lc; ++n) {
        float val = 0.f;
        if (n >= k) {
          if (n > k) { C = __fdividef(C * (float)n, (float)(n - k)); pd *= 0.1f; }
          val = C * pd * p9;           // C(n,n-k) P^(n-k) (1-P)^k
        }
        pnd[n] = val;
      }
      // plen[k] = Es[k] * prod_{t<k}(1-Es[t])  (redundant-parallel product)
      float cp = 1.f;
#pragma unroll
      for (int t2 = 0; t2 < Lc; ++t2) if (t2 < k) cp *= (1.f - Es[t2]);
      cp = fminf(cp, 1.f);
      plen[k] = (k < Lc) ? Es[k] * cp : cp;
    }
    if (k <= Lc) {                     // plen visible: same wave, prog order
      float s = 0.f;
#pragma unroll
      for (int n = 0; n <= Lc; ++n) s += plen[n] * pnd[n];
      As[k] = s;                       // adjusted length dist, linear
    }
    if (k < Lc) {                      // rem_k = 1 - prefix_sum(As)
      float pre = 0.f;
#pragma unroll
      for (int t2 = 0; t2 < Lc; ++t2) if (t2 < k) pre += As[t2];
      const float rem = fmaxf(1.f - pre, 1e-30f);
      const float r = fminf(__fdividef(As[k], rem), 1.f);
      eadj[k]   = fmaxf(__logf(r), FMIN);
      l1madj[k] = __logf(1.f - r);     // == log1p(-r) within fp32 tolerance
    }
  }
  __syncthreads();

  // ---- final: noisy + adjusted (expected already ~softmax-normalized) ----
  for (int idx = tid; idx < Lc * Vc; idx += 256) {
    const int i = idx >> 5, v = idx & 31;
    float nv;
    if (i >= Lc - ndel_s) nv = (v == 0) ? 1.f : 0.f;
    else                  nv = msg_s[ordv[i] * Vc + v];
    out_noisy[idx] = nv;
    float av;
    if (v == 0) {
      av = eadj[i];
    } else {
      float s = 0.f;
#pragma unroll
      for (int j = 0; j < Lc; ++j) s += Wf[i][j] * e[j][v - 1];
      av = __logf(s) + l1madj[i];
    }
    out_adj[idx] = av;
  }
}

} // namespace

extern "C" void kernel_launch(void* const* d_in, const int* in_sizes, int n_in,
                              void* d_out, int out_size, void* d_ws, size_t ws_size,
                              hipStream_t stream) {
  const float* messages = (const float*)d_in[0];
  const float* logits   = (const float*)d_in[1];
  const int*   mask     = (const int*)d_in[2];
  float* out = (float*)d_out;
  del_channel<<<Bc, 256, 0, stream>>>(messages, logits, mask, out);
}